// Round 21
// baseline (192.694 us; speedup 1.0000x reference)
//
#include <hip/hip_runtime.h>
#include <math.h>

#define XROWS 12544      // 256*49
#define YROWS 2048       // 64*32
#define HD 512
#define NM 49
#define NL 32
#define MP1 50
#define LP1 33
#define BSTRIDE 1650     // (m+1)*(L+1)
#define INVREG 10.0f

typedef __attribute__((ext_vector_type(8))) short short8;
typedef __attribute__((ext_vector_type(4))) float floatx4;
typedef _Float16 half2_t __attribute__((ext_vector_type(2)));

__device__ __forceinline__ unsigned short f2bf(float f) {
    unsigned int u = __builtin_bit_cast(unsigned int, f);
    u = (u + 0x7FFFu + ((u >> 16) & 1u)) >> 16;
    return (unsigned short)u;
}
__device__ __forceinline__ unsigned short f16b(float v) {
    return __builtin_bit_cast(unsigned short, (_Float16)v);
}

__device__ __forceinline__ float rl(float v, int l) {   // wave-uniform broadcast (SGPR)
    return __builtin_bit_cast(float, __builtin_amdgcn_readlane(__builtin_bit_cast(int, v), l));
}
__device__ __forceinline__ half2_t rlh2(unsigned v, int l) {
    return __builtin_bit_cast(half2_t, (unsigned)__builtin_amdgcn_readlane((int)v, l));
}
__device__ __forceinline__ float fdot2(half2_t a, half2_t b, float c) {
    return __builtin_amdgcn_fdot2(a, b, c, false);
}

// ------------------------------------------------ normalize + cast to bf16
__global__ __launch_bounds__(256) void normcvt_kernel(
    const float* __restrict__ x, const float* __restrict__ y,
    unsigned short* __restrict__ xb, unsigned short* __restrict__ yb)
{
    const int wid = blockIdx.x * 4 + (threadIdx.x >> 6);
    const int lane = threadIdx.x & 63;
    if (wid >= XROWS + YROWS) return;
    const float* src;
    unsigned short* dst;
    if (wid < XROWS) { src = x + (size_t)wid * HD;           dst = xb + (size_t)wid * HD; }
    else             { src = y + (size_t)(wid - XROWS) * HD; dst = yb + (size_t)(wid - XROWS) * HD; }
    const float4 v0 = *(const float4*)(src + lane * 8);
    const float4 v1 = *(const float4*)(src + lane * 8 + 4);
    float s = v0.x*v0.x + v0.y*v0.y + v0.z*v0.z + v0.w*v0.w
            + v1.x*v1.x + v1.y*v1.y + v1.z*v1.z + v1.w*v1.w;
    #pragma unroll
    for (int o = 32; o > 0; o >>= 1) s += __shfl_xor(s, o, 64);
    const float inv = 1.0f / fmaxf(sqrtf(s), 1e-12f);
    short8 ov;
    ov[0] = (short)f2bf(v0.x * inv); ov[1] = (short)f2bf(v0.y * inv);
    ov[2] = (short)f2bf(v0.z * inv); ov[3] = (short)f2bf(v0.w * inv);
    ov[4] = (short)f2bf(v1.x * inv); ov[5] = (short)f2bf(v1.y * inv);
    ov[6] = (short)f2bf(v1.z * inv); ov[7] = (short)f2bf(v1.w * inv);
    *(short8*)(dst + lane * 8) = ov;
}

// ------------------------------------------------ fused: block = image i x 8 langs
// No x LDS-stage: XCD swizzle (r18) keeps x_i L2-resident for all 8 sibling
// blocks, so MFMA A-frags read straight from L2. Per-wave LDS = 3.4 KB f16
// col-major T only -> 27.6 KB/block -> 4 blocks/CU (was 2-3 at 52.9 KB).
// K = exp(10s) computed once in acc layout, f16-scattered to T (NOT kept in
// regs - r19's mistake); kr2/kc2 both from T. Epilogue recomputes exp from
// acc and stores Zm DIRECTLY to global in acc layout (16-lane 64B runs).
// Waves fully independent: zero block barriers.
__global__ __launch_bounds__(512) void fused_kernel(
    const unsigned short* __restrict__ xb, const unsigned short* __restrict__ yb,
    const int* __restrict__ ymask,
    const float* __restrict__ d_im, const float* __restrict__ d_lang,
    float* __restrict__ outZ, float* __restrict__ scores2)
{
    const int wv   = threadIdx.x >> 6;        // 0..7
    const int lane = threadIdx.x & 63;
    const int i  = blockIdx.x & 255;          // XCD-locality swizzle
    const int jg = blockIdx.x >> 8;
    const int j  = jg * 8 + wv;
    const int pair = i * 64 + j;
    __shared__ alignas(16) unsigned short TAll[8][1728];   // 27.6 KB total
    unsigned short* T = TAll[wv];             // col-major [33][52] f16 K
    float* base = outZ + (size_t)pair * BSTRIDE;

    // ---- masks / dustbins ----
    const int mval = (lane < NL) ? (ymask[j * NL + lane] != 0) : 1;
    const unsigned long long vbm = __ballot(lane < NL && !mval);  // bit c = col valid
    const float ns = (float)__popcll(vbm);
    const float kim   = __expf(fminf(fmaxf(d_im[0],   -1.f), 1.f) * INVREG);
    const float klang = __expf(fminf(fmaxf(d_lang[0], -1.f), 1.f) * INVREG);

    // ---- scores via MFMA (A and B both from L2-resident global) ----
    const int la = lane & 15;
    const int koff = (lane >> 4) * 8;
    const unsigned short* xr0 = xb + ((size_t)i * NM + la) * HD + koff;
    const unsigned short* xr1 = xr0 + 16 * HD;
    const unsigned short* xr2 = xr0 + 32 * HD;
    const unsigned short* xr3 = xb + ((size_t)i * NM + 48) * HD + koff;  // row 48 uniform
    const unsigned short* yr0 = yb + ((size_t)j * NL + la) * HD + koff;
    const unsigned short* yr1 = yr0 + 16 * HD;

    floatx4 acc[4][2] = {};
    #pragma unroll
    for (int kt = 0; kt < 16; ++kt) {
        const int k0 = kt * 32;
        const short8 a0 = *(const short8*)(xr0 + k0);
        const short8 a1 = *(const short8*)(xr1 + k0);
        const short8 a2 = *(const short8*)(xr2 + k0);
        const short8 a3 = *(const short8*)(xr3 + k0);
        const short8 b0 = *(const short8*)(yr0 + k0);
        const short8 b1 = *(const short8*)(yr1 + k0);
        acc[0][0] = __builtin_amdgcn_mfma_f32_16x16x32_bf16(a0, b0, acc[0][0], 0, 0, 0);
        acc[0][1] = __builtin_amdgcn_mfma_f32_16x16x32_bf16(a0, b1, acc[0][1], 0, 0, 0);
        acc[1][0] = __builtin_amdgcn_mfma_f32_16x16x32_bf16(a1, b0, acc[1][0], 0, 0, 0);
        acc[1][1] = __builtin_amdgcn_mfma_f32_16x16x32_bf16(a1, b1, acc[1][1], 0, 0, 0);
        acc[2][0] = __builtin_amdgcn_mfma_f32_16x16x32_bf16(a2, b0, acc[2][0], 0, 0, 0);
        acc[2][1] = __builtin_amdgcn_mfma_f32_16x16x32_bf16(a2, b1, acc[2][1], 0, 0, 0);
        acc[3][0] = __builtin_amdgcn_mfma_f32_16x16x32_bf16(a3, b0, acc[3][0], 0, 0, 0);
        acc[3][1] = __builtin_amdgcn_mfma_f32_16x16x32_bf16(a3, b1, acc[3][1], 0, 0, 0);
    }

    // ---- K = exp(10s) once in acc layout -> f16 scatter to col-major T ----
    const bool mA = (vbm >> la) & 1ull;         // col la valid
    const bool mB = (vbm >> (16 + la)) & 1ull;  // col 16+la valid
    #pragma unroll
    for (int mi = 0; mi < 3; ++mi) {            // rows 0..47, b64 writes
        const int r0 = mi * 16 + ((lane >> 4) << 2);
        ushort4 wa, wb;
        wa.x = f16b(mA ? __expf(acc[mi][0][0] * INVREG) : 0.f);
        wa.y = f16b(mA ? __expf(acc[mi][0][1] * INVREG) : 0.f);
        wa.z = f16b(mA ? __expf(acc[mi][0][2] * INVREG) : 0.f);
        wa.w = f16b(mA ? __expf(acc[mi][0][3] * INVREG) : 0.f);
        wb.x = f16b(mB ? __expf(acc[mi][1][0] * INVREG) : 0.f);
        wb.y = f16b(mB ? __expf(acc[mi][1][1] * INVREG) : 0.f);
        wb.z = f16b(mB ? __expf(acc[mi][1][2] * INVREG) : 0.f);
        wb.w = f16b(mB ? __expf(acc[mi][1][3] * INVREG) : 0.f);
        *(ushort4*)(T + la * 52 + r0)        = wa;
        *(ushort4*)(T + (16 + la) * 52 + r0) = wb;
    }
    if ((lane >> 4) == 0) {                     // row 48
        T[la * 52 + 48]        = f16b(mA ? __expf(acc[3][0][0] * INVREG) : 0.f);
        T[(16 + la) * 52 + 48] = f16b(mB ? __expf(acc[3][1][0] * INVREG) : 0.f);
    }
    if (lane < NL)       T[lane * 52 + 49] = f16b(((vbm >> lane) & 1ull) ? klang : 0.f);
    else if (lane == NL) T[32 * 52 + 49]   = f16b(kim);   // alpha corner
    if (lane < NM)       T[32 * 52 + lane] = f16b(kim);   // dustbin col rows 0..48
    asm volatile("s_waitcnt lgkmcnt(0)" ::: "memory");
    __builtin_amdgcn_sched_barrier(0);

    // ---- kr2 (row layout) and kc2 (col layout) from T ----
    half2_t kr2[17];
    {
        const int p = (lane < MP1) ? lane : 0;
        #pragma unroll
        for (int q = 0; q < 16; ++q) {
            const unsigned lo = T[(2*q)   * 52 + p];
            const unsigned hi = T[(2*q+1) * 52 + p];
            kr2[q] = __builtin_bit_cast(half2_t, lo | (hi << 16));
        }
        half2_t h; h[0] = (_Float16)kim; h[1] = (_Float16)0.f;
        kr2[16] = h;
    }
    half2_t kc2[25];
    {
        const int tb = ((lane < LP1) ? lane : 0) * 52;
        #pragma unroll
        for (int q = 0; q < 25; ++q)            // pairs cover p = 0..49 exactly
            kc2[q] = __builtin_bit_cast(half2_t, *(const unsigned*)(T + tb + 2*q));
    }

    const float mup = (lane < NM) ? 1.f : ns;     // lane 49 -> ns
    const float nup = (lane < NL) ? 1.f : 49.f;   // lane 32 -> m
    const bool colA = (lane < NL) ? (((vbm >> lane) & 1ull) != 0ull) : (lane == NL);
    float eu = 0.f;
    float ev = colA ? 1.f : 0.f;

    // ---- 10 iterations: packed-f16 broadcasts + dot2 (f32 accumulate) ----
    for (int it = 0; it < 10; ++it) {
        const float evn = __shfl_xor(ev, 1, 64);
        half2_t evp; evp[0] = (_Float16)ev; evp[1] = (_Float16)evn;
        const unsigned evpu = __builtin_bit_cast(unsigned, evp);
        float a0 = 0.f, a1 = 0.f;
        #pragma unroll
        for (int q = 0; q < 17; q += 2) {
            a0 = fdot2(kr2[q], rlh2(evpu, 2*q), a0);
            if (q + 1 < 17) a1 = fdot2(kr2[q+1], rlh2(evpu, 2*q+2), a1);
        }
        eu = __fdividef(mup, a0 + a1);

        const float eun = __shfl_xor(eu, 1, 64);
        half2_t eup; eup[0] = (_Float16)eu; eup[1] = (_Float16)eun;
        const unsigned eupu = __builtin_bit_cast(unsigned, eup);
        float b0 = 0.f, b1 = 0.f;
        #pragma unroll
        for (int q = 0; q < 25; q += 2) {
            b0 = fdot2(kc2[q], rlh2(eupu, 2*q), b0);
            if (q + 1 < 25) b1 = fdot2(kc2[q+1], rlh2(eupu, 2*q+2), b1);
        }
        const float Sv = b0 + b1;
        ev = colA ? __fdividef(nup, Sv) : 0.f;
    }

    // ---- epilogue in ACC LAYOUT, direct global stores (16-lane 64B runs) ----
    const float ev32 = rl(ev, 32);
    const float eu49 = rl(eu, 49);
    const float evA  = __shfl(ev, la, 64);        // ev[col=la] (0 for masked)
    const float evB  = __shfl(ev, 16 + la, 64);   // ev[col=16+la]
    float ot = 0.f;
    #pragma unroll
    for (int mi = 0; mi < 4; ++mi) {
        #pragma unroll
        for (int q = 0; q < 4; ++q) {
            const int row = mi * 16 + ((lane >> 4) << 2) + q;
            const float eur = __shfl(eu, row, 64);
            if (row < NM) {
                const float s0 = acc[mi][0][q];
                const float s1 = acc[mi][1][q];
                const float zm0 = __expf(s0 * INVREG) * eur * evA;
                const float zm1 = __expf(s1 * INVREG) * eur * evB;
                base[row * 33 + la]      = zm0;
                base[row * 33 + 16 + la] = zm1;
                ot = fmaf(s0 * INVREG, zm0, fmaf(s1 * INVREG, zm1, ot));
            }
        }
    }
    // dustbin col 32 (rows 0..49) and row 49 (cols 0..32)
    if (lane < MP1) base[lane * 33 + 32] = kim * eu * ev32;
    if (lane < LP1) {
        const float kd = (lane < NL) ? (((vbm >> lane) & 1ull) ? klang : 0.f) : kim;
        base[NM * 33 + lane] = kd * eu49 * ev;
    }
    #pragma unroll
    for (int o = 32; o > 0; o >>= 1) ot += __shfl_xor(ot, o, 64);
    if (lane == 0) scores2[pair] = ot;
}

// ---------------------------------------------------------------- InfoNCE loss
// LDS-staged; lse_im via shared per-column base sums.
__global__ __launch_bounds__(256) void loss_kernel(
    const float* __restrict__ s2, float* __restrict__ out)
{
    __shared__ float S2[16384];                 // 64 KB
    __shared__ float colmax[64], colsum[64];
    __shared__ float wred[4];
    const int tid = threadIdx.x;
    for (int t = tid; t < 4096; t += 256)
        ((float4*)S2)[t] = ((const float4*)s2)[t];
    __syncthreads();

    // ---- column stats: 4 threads per column g ----
    const int gc = tid >> 2, sc = tid & 3;
    float cm = -3.0e38f;
    for (int k = sc * 64; k < sc * 64 + 64; ++k) cm = fmaxf(cm, S2[k * 64 + gc]);
    cm = fmaxf(cm, __shfl_xor(cm, 1, 64));
    cm = fmaxf(cm, __shfl_xor(cm, 2, 64));
    float cs = 0.f;
    for (int k = sc * 64; k < sc * 64 + 64; ++k)
        if ((k >> 2) != gc) cs += __expf(S2[k * 64 + gc] - cm);
    cs += __shfl_xor(cs, 1, 64);
    cs += __shfl_xor(cs, 2, 64);
    if (sc == 0) { colmax[gc] = cm; colsum[gc] = cs; }
    __syncthreads();

    // ---- per image ----
    const int i = tid;
    const int g = i >> 2;
    const float pos = S2[i * 64 + g];
    float mx = -3.0e38f;
    for (int jj = 0; jj < 64; ++jj) {           // rotated index -> no bank aliasing
        const int c = (jj + i) & 63;
        mx = fmaxf(mx, S2[i * 64 + c]);
    }
    float sm = 0.f;
    for (int jj = 0; jj < 64; ++jj) {
        const int c = (jj + i) & 63;
        sm += __expf(S2[i * 64 + c] - mx);
    }
    const float lse1 = __logf(sm) + mx;

    const float cmg = colmax[g], csg = colsum[g];
    const float lse2 = __logf(csg + __expf(pos - cmg)) + cmg;

    float li = 0.5f * (lse1 - pos) + 0.5f * (lse2 - pos);
    #pragma unroll
    for (int o = 32; o > 0; o >>= 1) li += __shfl_xor(li, o, 64);
    if ((i & 63) == 0) wred[i >> 6] = li;
    __syncthreads();
    if (i == 0) out[0] = (wred[0] + wred[1] + wred[2] + wred[3]) * (1.0f / 256.0f);
}

// ---------------------------------------------------------------- launch
extern "C" void kernel_launch(void* const* d_in, const int* in_sizes, int n_in,
                              void* d_out, int out_size, void* d_ws, size_t ws_size,
                              hipStream_t stream)
{
    const float* x      = (const float*)d_in[0];
    const float* y      = (const float*)d_in[1];
    const float* d_im   = (const float*)d_in[2];
    const float* d_lang = (const float*)d_in[3];
    const int* ymask    = (const int*)d_in[4];
    float* out = (float*)d_out;
    float* ws  = (float*)d_ws;

    float* s2          = ws;                                  // 16384 floats
    unsigned short* xb = (unsigned short*)(ws + 16384);       // 12544*512 bf16
    unsigned short* yb = xb + (size_t)XROWS * HD;             // 2048*512 bf16

    normcvt_kernel<<<(XROWS + YROWS + 3) / 4, 256, 0, stream>>>(x, y, xb, yb);
    fused_kernel<<<2048, 512, 0, stream>>>(xb, yb, ymask, d_im, d_lang, out, s2);
    loss_kernel<<<1, 256, 0, stream>>>(s2, out + (size_t)16384 * BSTRIDE);
}

// Round 22
// 117.346 us; speedup vs baseline: 1.6421x; 1.6421x over previous
//
#include <hip/hip_runtime.h>
#include <math.h>

#define XROWS 12544      // 256*49
#define YROWS 2048       // 64*32
#define HD 512
#define NM 49
#define NL 32
#define MP1 50
#define LP1 33
#define BSTRIDE 1650     // (m+1)*(L+1)
#define INVREG 10.0f
#define ZSTR 1652        // per-wave zs floats (rowtile<=1648, T(u16)<=1713B region, Zm<=1649)

typedef __attribute__((ext_vector_type(8))) short short8;
typedef __attribute__((ext_vector_type(4))) float floatx4;
typedef _Float16 half2_t __attribute__((ext_vector_type(2)));

__device__ __forceinline__ unsigned short f2bf(float f) {
    unsigned int u = __builtin_bit_cast(unsigned int, f);
    u = (u + 0x7FFFu + ((u >> 16) & 1u)) >> 16;
    return (unsigned short)u;
}

__device__ __forceinline__ void gload_lds16(const void* g, void* l) {
    typedef const __attribute__((address_space(1))) unsigned int* gp_t;
    typedef __attribute__((address_space(3))) unsigned int* lp_t;
    __builtin_amdgcn_global_load_lds((gp_t)g, (lp_t)l, 16, 0, 0);
}

__device__ __forceinline__ float rl(float v, int l) {   // wave-uniform broadcast (SGPR)
    return __builtin_bit_cast(float, __builtin_amdgcn_readlane(__builtin_bit_cast(int, v), l));
}
__device__ __forceinline__ half2_t rlh2(unsigned v, int l) {
    return __builtin_bit_cast(half2_t, (unsigned)__builtin_amdgcn_readlane((int)v, l));
}
__device__ __forceinline__ float fdot2(half2_t a, half2_t b, float c) {
    return __builtin_amdgcn_fdot2(a, b, c, false);
}

// ------------------------------------------------ normalize + cast to bf16
__global__ __launch_bounds__(256) void normcvt_kernel(
    const float* __restrict__ x, const float* __restrict__ y,
    unsigned short* __restrict__ xb, unsigned short* __restrict__ yb)
{
    const int wid = blockIdx.x * 4 + (threadIdx.x >> 6);
    const int lane = threadIdx.x & 63;
    if (wid >= XROWS + YROWS) return;
    const float* src;
    unsigned short* dst;
    if (wid < XROWS) { src = x + (size_t)wid * HD;           dst = xb + (size_t)wid * HD; }
    else             { src = y + (size_t)(wid - XROWS) * HD; dst = yb + (size_t)(wid - XROWS) * HD; }
    const float4 v0 = *(const float4*)(src + lane * 8);
    const float4 v1 = *(const float4*)(src + lane * 8 + 4);
    float s = v0.x*v0.x + v0.y*v0.y + v0.z*v0.z + v0.w*v0.w
            + v1.x*v1.x + v1.y*v1.y + v1.z*v1.z + v1.w*v1.w;
    #pragma unroll
    for (int o = 32; o > 0; o >>= 1) s += __shfl_xor(s, o, 64);
    const float inv = 1.0f / fmaxf(sqrtf(s), 1e-12f);
    short8 ov;
    ov[0] = (short)f2bf(v0.x * inv); ov[1] = (short)f2bf(v0.y * inv);
    ov[2] = (short)f2bf(v0.z * inv); ov[3] = (short)f2bf(v0.w * inv);
    ov[4] = (short)f2bf(v1.x * inv); ov[5] = (short)f2bf(v1.y * inv);
    ov[6] = (short)f2bf(v1.z * inv); ov[7] = (short)f2bf(v1.w * inv);
    *(short8*)(dst + lane * 8) = ov;
}

// ------------------------------------------------ fused: block = image i x 8 langs
// (r20/r18 configuration — verified fused 107.4 us, total 117.6 us)
// XCD-aware decode: i = blockIdx&255 -> all 8 blocks sharing x_i on one XCD L2.
// Phase A: stage x_i once to LDS. Phase B: per-wave 49x32 scores via MFMA.
// Phase C: sinkhorn, K as f16 pairs + packed readlane + dot2.
// Epilogue: Zm in ACC LAYOUT (exp from raw score; eu/ev via shfl), no logf.
__global__ __launch_bounds__(512) void fused_kernel(
    const unsigned short* __restrict__ xb, const unsigned short* __restrict__ yb,
    const int* __restrict__ ymask,
    const float* __restrict__ d_im, const float* __restrict__ d_lang,
    float* __restrict__ outZ, float* __restrict__ scores2)
{
    const int wv   = threadIdx.x >> 6;        // 0..7
    const int lane = threadIdx.x & 63;
    const int i  = blockIdx.x & 255;          // XCD-locality swizzle
    const int jg = blockIdx.x >> 8;
    const int j  = jg * 8 + wv;
    const int pair = i * 64 + j;
    __shared__ alignas(16) float LDSU[8 * ZSTR];  // 52.9 KB; x-stage unions wave scratch
    char* XSB = (char*)LDSU;                      // x-stage: 49 rows x 1040 B = 51.0 KB
    float* zs = LDSU + wv * ZSTR;                 // rowtile / u16-transpose / Zm staging
    float* base = outZ + (size_t)pair * BSTRIDE;

    // ---- phase A: stage x_i rows (row stride 1040 B) ----
    #pragma unroll
    for (int pass = 0; pass < 7; ++pass) {
        const int row = pass * 8 + wv;
        if (row < NM)
            gload_lds16(xb + ((size_t)i * NM + row) * HD + lane * 8, XSB + row * 1040);
    }
    __syncthreads();                            // drains vmcnt; stage visible to all

    // ---- masks / dustbins ----
    const int mval = (lane < NL) ? (ymask[j * NL + lane] != 0) : 1;
    const unsigned long long vbm = __ballot(lane < NL && !mval);  // bit c = col valid
    const float ns = (float)__popcll(vbm);
    const float kim   = __expf(fminf(fmaxf(d_im[0],   -1.f), 1.f) * INVREG);
    const float klang = __expf(fminf(fmaxf(d_lang[0], -1.f), 1.f) * INVREG);

    // ---- phase B: scores via MFMA ----
    const int la = lane & 15;
    const int koff = (lane >> 4) * 8;
    const unsigned short* yr0 = yb + ((size_t)j * NL + la) * HD + koff;
    const unsigned short* yr1 = yr0 + 16 * HD;

    floatx4 acc[4][2] = {};
    #pragma unroll
    for (int kt = 0; kt < 16; ++kt) {
        const int kb = (kt * 32 + koff) * 2;    // byte offset within padded row
        const short8 a0 = *(const short8*)(XSB + (0  + la) * 1040 + kb);
        const short8 a1 = *(const short8*)(XSB + (16 + la) * 1040 + kb);
        const short8 a2 = *(const short8*)(XSB + (32 + la) * 1040 + kb);
        const short8 a3 = *(const short8*)(XSB + 48 * 1040 + kb);   // uniform row 48
        const short8 b0 = *(const short8*)(yr0 + kt * 32);
        const short8 b1 = *(const short8*)(yr1 + kt * 32);
        acc[0][0] = __builtin_amdgcn_mfma_f32_16x16x32_bf16(a0, b0, acc[0][0], 0, 0, 0);
        acc[0][1] = __builtin_amdgcn_mfma_f32_16x16x32_bf16(a0, b1, acc[0][1], 0, 0, 0);
        acc[1][0] = __builtin_amdgcn_mfma_f32_16x16x32_bf16(a1, b0, acc[1][0], 0, 0, 0);
        acc[1][1] = __builtin_amdgcn_mfma_f32_16x16x32_bf16(a1, b1, acc[1][1], 0, 0, 0);
        acc[2][0] = __builtin_amdgcn_mfma_f32_16x16x32_bf16(a2, b0, acc[2][0], 0, 0, 0);
        acc[2][1] = __builtin_amdgcn_mfma_f32_16x16x32_bf16(a2, b1, acc[2][1], 0, 0, 0);
        acc[3][0] = __builtin_amdgcn_mfma_f32_16x16x32_bf16(a3, b0, acc[3][0], 0, 0, 0);
        acc[3][1] = __builtin_amdgcn_mfma_f32_16x16x32_bf16(a3, b1, acc[3][1], 0, 0, 0);
    }
    __syncthreads();                            // x-LDS reads done -> scratch reuse safe

    // ---- repack acc -> zs row-major stride 33 (for kr build only) ----
    #pragma unroll
    for (int mi = 0; mi < 4; ++mi) {
        #pragma unroll
        for (int q = 0; q < 4; ++q) {
            const int row = mi * 16 + (lane >> 4) * 4 + q;
            if (row < MP1) {
                zs[row * 33 + la]      = acc[mi][0][q];
                zs[row * 33 + 16 + la] = acc[mi][1][q];
            }
        }
    }
    asm volatile("s_waitcnt lgkmcnt(0)" ::: "memory");
    __builtin_amdgcn_sched_barrier(0);

    // ---- krf[33] from zs (lane p = row p) ----
    float krf[33];
    #pragma unroll
    for (int c = 0; c < 33; ++c) krf[c] = 0.f;
    if (lane < NM) {
        #pragma unroll
        for (int c = 0; c < NL; ++c) {
            const float sc = zs[lane * 33 + c];
            krf[c] = ((vbm >> c) & 1ull) ? __expf(sc * INVREG) : 0.f;
        }
    } else if (lane == NM) {                    // dustbin row p=49
        #pragma unroll
        for (int c = 0; c < NL; ++c) krf[c] = ((vbm >> c) & 1ull) ? klang : 0.f;
    }
    krf[32] = kim;
    asm volatile("s_waitcnt lgkmcnt(0)" ::: "memory");
    __builtin_amdgcn_sched_barrier(0);

    // ---- pack K row to f16 pairs ----
    half2_t kr2[17];
    #pragma unroll
    for (int q = 0; q < 16; ++q) {
        half2_t h; h[0] = (_Float16)krf[2*q]; h[1] = (_Float16)krf[2*q+1];
        kr2[q] = h;
    }
    { half2_t h; h[0] = (_Float16)krf[32]; h[1] = (_Float16)0.f; kr2[16] = h; }

    // ---- one-time u16 transpose: T[c*52 + p] ----
    unsigned short* T = (unsigned short*)zs;
    if (lane < MP1) {
        #pragma unroll
        for (int c = 0; c < 33; ++c)
            T[c * 52 + lane] = __builtin_bit_cast(unsigned short, (_Float16)krf[c]);
    }
    asm volatile("s_waitcnt lgkmcnt(0)" ::: "memory");
    __builtin_amdgcn_sched_barrier(0);
    half2_t kc2[25];
    {
        const int tb = ((lane < LP1) ? lane : 0) * 52;
        #pragma unroll
        for (int q = 0; q < 25; ++q)
            kc2[q] = __builtin_bit_cast(half2_t, *(const unsigned*)(T + tb + 2*q));
    }

    const float mup = (lane < NM) ? 1.f : ns;     // lane 49 -> ns
    const float nup = (lane < NL) ? 1.f : 49.f;   // lane 32 -> m
    const bool colA = (lane < NL) ? (((vbm >> lane) & 1ull) != 0ull) : (lane == NL);
    float eu = 0.f;
    float ev = colA ? 1.f : 0.f;

    // ---- 10 iterations: packed-f16 broadcasts + dot2 (f32 accumulate) ----
    for (int it = 0; it < 10; ++it) {
        const float evn = __shfl_xor(ev, 1, 64);
        half2_t evp; evp[0] = (_Float16)ev; evp[1] = (_Float16)evn;
        const unsigned evpu = __builtin_bit_cast(unsigned, evp);
        float a0 = 0.f, a1 = 0.f;
        #pragma unroll
        for (int q = 0; q < 17; q += 2) {
            a0 = fdot2(kr2[q], rlh2(evpu, 2*q), a0);
            if (q + 1 < 17) a1 = fdot2(kr2[q+1], rlh2(evpu, 2*q+2), a1);
        }
        eu = __fdividef(mup, a0 + a1);

        const float eun = __shfl_xor(eu, 1, 64);
        half2_t eup; eup[0] = (_Float16)eu; eup[1] = (_Float16)eun;
        const unsigned eupu = __builtin_bit_cast(unsigned, eup);
        float b0 = 0.f, b1 = 0.f;
        #pragma unroll
        for (int q = 0; q < 25; q += 2) {
            b0 = fdot2(kc2[q], rlh2(eupu, 2*q), b0);
            if (q + 1 < 25) b1 = fdot2(kc2[q+1], rlh2(eupu, 2*q+2), b1);
        }
        const float Sv = b0 + b1;
        ev = colA ? __fdividef(nup, Sv) : 0.f;
    }

    // ---- epilogue in ACC LAYOUT: zm = exp(10s)*eu[row]*ev[col]; ot = 10s*zm ----
    const float ev32 = rl(ev, 32);
    const float eu49 = rl(eu, 49);
    const float evA  = __shfl(ev, la, 64);        // ev[col=la] (0 for masked)
    const float evB  = __shfl(ev, 16 + la, 64);   // ev[col=16+la]
    float ot = 0.f;
    #pragma unroll
    for (int mi = 0; mi < 4; ++mi) {
        #pragma unroll
        for (int q = 0; q < 4; ++q) {
            const int row = mi * 16 + ((lane >> 4) << 2) + q;
            const float eur = __shfl(eu, row, 64);
            if (row < NM) {
                const float s0 = acc[mi][0][q];
                const float s1 = acc[mi][1][q];
                const float zm0 = __expf(s0 * INVREG) * eur * evA;
                const float zm1 = __expf(s1 * INVREG) * eur * evB;
                zs[row * 33 + la]      = zm0;
                zs[row * 33 + 16 + la] = zm1;
                ot = fmaf(s0 * INVREG, zm0, fmaf(s1 * INVREG, zm1, ot));
            }
        }
    }
    // dustbin col 32 (rows 0..49) and row 49 (cols 0..32)
    if (lane < MP1) zs[lane * 33 + 32] = kim * eu * ev32;
    if (lane < LP1) {
        const float kd = (lane < NL) ? (((vbm >> lane) & 1ull) ? klang : 0.f) : kim;
        zs[NM * 33 + lane] = kd * eu49 * ev;
    }
    #pragma unroll
    for (int o = 32; o > 0; o >>= 1) ot += __shfl_xor(ot, o, 64);
    if (lane == 0) scores2[pair] = ot;
    asm volatile("s_waitcnt lgkmcnt(0)" ::: "memory");
    __builtin_amdgcn_sched_barrier(0);
    // coalesced writeback: 1650 floats = 825 float2
    #pragma unroll
    for (int t = 0; t < 13; ++t) {
        const int idx = t * 64 + lane;
        if (idx < 825) *(float2*)(base + idx * 2) = *(const float2*)&zs[idx * 2];
    }
}

// ---------------------------------------------------------------- InfoNCE loss
// LDS-staged; lse_im via shared per-column base sums (4 images/column share
// the excluded-group sum; the k==i term is patched back per image).
__global__ __launch_bounds__(256) void loss_kernel(
    const float* __restrict__ s2, float* __restrict__ out)
{
    __shared__ float S2[16384];                 // 64 KB
    __shared__ float colmax[64], colsum[64];
    __shared__ float wred[4];
    const int tid = threadIdx.x;
    for (int t = tid; t < 4096; t += 256)
        ((float4*)S2)[t] = ((const float4*)s2)[t];
    __syncthreads();

    // ---- column stats: 4 threads per column g ----
    const int gc = tid >> 2, sc = tid & 3;
    float cm = -3.0e38f;
    for (int k = sc * 64; k < sc * 64 + 64; ++k) cm = fmaxf(cm, S2[k * 64 + gc]);
    cm = fmaxf(cm, __shfl_xor(cm, 1, 64));
    cm = fmaxf(cm, __shfl_xor(cm, 2, 64));
    float cs = 0.f;
    for (int k = sc * 64; k < sc * 64 + 64; ++k)
        if ((k >> 2) != gc) cs += __expf(S2[k * 64 + gc] - cm);
    cs += __shfl_xor(cs, 1, 64);
    cs += __shfl_xor(cs, 2, 64);
    if (sc == 0) { colmax[gc] = cm; colsum[gc] = cs; }
    __syncthreads();

    // ---- per image ----
    const int i = tid;
    const int g = i >> 2;
    const float pos = S2[i * 64 + g];
    float mx = -3.0e38f;
    for (int jj = 0; jj < 64; ++jj) {           // rotated index -> no bank aliasing
        const int c = (jj + i) & 63;
        mx = fmaxf(mx, S2[i * 64 + c]);
    }
    float sm = 0.f;
    for (int jj = 0; jj < 64; ++jj) {
        const int c = (jj + i) & 63;
        sm += __expf(S2[i * 64 + c] - mx);
    }
    const float lse1 = __logf(sm) + mx;

    const float cmg = colmax[g], csg = colsum[g];
    const float lse2 = __logf(csg + __expf(pos - cmg)) + cmg;

    float li = 0.5f * (lse1 - pos) + 0.5f * (lse2 - pos);
    #pragma unroll
    for (int o = 32; o > 0; o >>= 1) li += __shfl_xor(li, o, 64);
    if ((i & 63) == 0) wred[i >> 6] = li;
    __syncthreads();
    if (i == 0) out[0] = (wred[0] + wred[1] + wred[2] + wred[3]) * (1.0f / 256.0f);
}

// ---------------------------------------------------------------- launch
extern "C" void kernel_launch(void* const* d_in, const int* in_sizes, int n_in,
                              void* d_out, int out_size, void* d_ws, size_t ws_size,
                              hipStream_t stream)
{
    const float* x      = (const float*)d_in[0];
    const float* y      = (const float*)d_in[1];
    const float* d_im   = (const float*)d_in[2];
    const float* d_lang = (const float*)d_in[3];
    const int* ymask    = (const int*)d_in[4];
    float* out = (float*)d_out;
    float* ws  = (float*)d_ws;

    float* s2          = ws;                                  // 16384 floats
    unsigned short* xb = (unsigned short*)(ws + 16384);       // 12544*512 bf16
    unsigned short* yb = xb + (size_t)XROWS * HD;             // 2048*512 bf16

    normcvt_kernel<<<(XROWS + YROWS + 3) / 4, 256, 0, stream>>>(x, y, xb, yb);
    fused_kernel<<<2048, 512, 0, stream>>>(xb, yb, ymask, d_im, d_lang, out, s2);
    loss_kernel<<<1, 256, 0, stream>>>(s2, out + (size_t)16384 * BSTRIDE);
}